// Round 12
// baseline (231.778 us; speedup 1.0000x reference)
//
#include <hip/hip_runtime.h>
#include <hip/hip_bf16.h>
#include <math.h>

#define BATCH 2
#define SEQ 1024
#define DMODEL 1024
#define DSTATE 128
#define HEADDIM 64
#define NHEADS 32
#define DINNER 2048
#define NUMANG 32
#define DPROJ 4480
#define CH 64
#define NCH 16
#define TAILSTART 4352
// proj row offsets (elements)
#define OFF_Z 0
#define OFF_X 2048
#define OFF_B 4096
#define OFF_C 4224
#define OFF_DT 4352
#define OFF_A 4384
#define OFF_TRAP 4416
#define OFF_ANG 4448

typedef __attribute__((ext_vector_type(8))) short bf16x8;
typedef __attribute__((ext_vector_type(4))) float f32x4;
typedef unsigned short u16;

__device__ __forceinline__ u16 f2bf(float f) {
  unsigned int u = __float_as_uint(f);
  u += 0x7FFFu + ((u >> 16) & 1u);
  return (u16)(u >> 16);
}
__device__ __forceinline__ float bf2f(u16 x) {
  return __uint_as_float(((unsigned int)x) << 16);
}

#define N4_U 524288
#define N4_WI 1146880
#define N4_WO 524288

__global__ __launch_bounds__(256) void cvt_all(const float* __restrict__ u,
                                               const float* __restrict__ Wi,
                                               const float* __restrict__ Wo,
                                               u16* __restrict__ ub16,
                                               u16* __restrict__ Wi16,
                                               u16* __restrict__ Wo16) {
  int i = blockIdx.x * 256 + threadIdx.x;
  const float4* src;
  ushort4* dst;
  int idx;
  if (i < N4_U) { src = (const float4*)u; dst = (ushort4*)ub16; idx = i; }
  else if (i < N4_U + N4_WI) { src = (const float4*)Wi; dst = (ushort4*)Wi16; idx = i - N4_U; }
  else if (i < N4_U + N4_WI + N4_WO) { src = (const float4*)Wo; dst = (ushort4*)Wo16; idx = i - N4_U - N4_WI; }
  else return;
  float4 v = src[idx];
  ushort4 o;
  o.x = f2bf(v.x); o.y = f2bf(v.y); o.z = f2bf(v.z); o.w = f2bf(v.w);
  dst[idx] = o;
}

__device__ __forceinline__ void gload_lds16(const void* g, void* l) {
  __builtin_amdgcn_global_load_lds(
      (const __attribute__((address_space(1))) unsigned int*)g,
      (__attribute__((address_space(3))) unsigned int*)l, 16, 0, 0);
}

// ==== 64x64-tile bf16 MFMA GEMM, C = A @ B^T, double-buffered staging ======
__global__ __launch_bounds__(256) void gemm_proj64(const u16* __restrict__ A,
                                                   const u16* __restrict__ B,
                                                   u16* __restrict__ Cb,
                                                   float* __restrict__ tailF,
                                                   int M, int N, int K) {
  __shared__ u16 As[2][64 * 64];
  __shared__ u16 Bs[2][64 * 64];
  const int tid = threadIdx.x;
  const int lane = tid & 63, wave = tid >> 6;
  const int bm = blockIdx.y * 64, bn = blockIdx.x * 64;
  const int wm = (wave >> 1) * 32, wn = (wave & 1) * 32;
  const int srow = wave * 8 + (lane >> 3);
  const int scol = (((lane & 7) ^ ((lane >> 3) & 7)) * 8);
  const u16* Ab = A + (size_t)(bm + srow) * K + scol;
  const u16* Bb = B + (size_t)(bn + srow) * K + scol;
  const int soff = wave * 512 + (lane & 7) * 8 + (lane >> 3) * 64;  // unused helper
  (void)soff;
  f32x4 acc[2][2];
#pragma unroll
  for (int i = 0; i < 2; ++i)
#pragma unroll
    for (int j = 0; j < 2; ++j) acc[i][j] = (f32x4){0.f, 0.f, 0.f, 0.f};
  const int fr = lane & 15, fq = lane >> 4, sw = fr & 7;

  // prologue: stage k0=0 into buffer 0
#pragma unroll
  for (int it = 0; it < 2; ++it) {
    gload_lds16(Ab + (size_t)(it * 32) * K, &As[0][wave * 512 + it * 2048]);
    gload_lds16(Bb + (size_t)(it * 32) * K, &Bs[0][wave * 512 + it * 2048]);
  }

  const int NIT = K >> 6;
  for (int itk = 0; itk < NIT; ++itk) {
    const int cur = itk & 1;
    __syncthreads();  // prefetch into cur complete; prev buffer free
    if (itk + 1 < NIT) {
      const int nk = (itk + 1) << 6;
      const int nxt = cur ^ 1;
#pragma unroll
      for (int it = 0; it < 2; ++it) {
        gload_lds16(Ab + (size_t)(it * 32) * K + nk, &As[nxt][wave * 512 + it * 2048]);
        gload_lds16(Bb + (size_t)(it * 32) * K + nk, &Bs[nxt][wave * 512 + it * 2048]);
      }
    }
#pragma unroll
    for (int kh = 0; kh < 2; ++kh) {
      bf16x8 af[2], bfv[2];
#pragma unroll
      for (int i = 0; i < 2; ++i)
        af[i] = *(const bf16x8*)(&As[cur][(wm + i * 16 + fr) * 64 + (((kh * 4 + fq) ^ sw) * 8)]);
#pragma unroll
      for (int j = 0; j < 2; ++j)
        bfv[j] = *(const bf16x8*)(&Bs[cur][(wn + j * 16 + fr) * 64 + (((kh * 4 + fq) ^ sw) * 8)]);
#pragma unroll
      for (int i = 0; i < 2; ++i)
#pragma unroll
        for (int j = 0; j < 2; ++j)
          acc[i][j] = __builtin_amdgcn_mfma_f32_16x16x32_bf16(af[i], bfv[j], acc[i][j], 0, 0, 0);
    }
  }
  const int orow = bm + wm + fq * 4;
  const int ocol = bn + wn + fr;
  const bool tail = (bn >= TAILSTART);
#pragma unroll
  for (int i = 0; i < 2; ++i)
#pragma unroll
    for (int j = 0; j < 2; ++j)
#pragma unroll
      for (int r = 0; r < 4; ++r) {
        float v = acc[i][j][r];
        int row = orow + i * 16 + r, col = ocol + j * 16;
        Cb[(size_t)row * N + col] = f2bf(v);
        if (tail) tailF[(size_t)row * 128 + (col - TAILSTART)] = v;
      }
}

__global__ __launch_bounds__(256) void gemm_out64(const u16* __restrict__ A,
                                                  const u16* __restrict__ B,
                                                  float* __restrict__ C,
                                                  int M, int N, int K) {
  __shared__ u16 As[2][64 * 64];
  __shared__ u16 Bs[2][64 * 64];
  const int tid = threadIdx.x;
  const int lane = tid & 63, wave = tid >> 6;
  const int bm = blockIdx.y * 64, bn = blockIdx.x * 64;
  const int wm = (wave >> 1) * 32, wn = (wave & 1) * 32;
  const int srow = wave * 8 + (lane >> 3);
  const int scol = (((lane & 7) ^ ((lane >> 3) & 7)) * 8);
  const u16* Ab = A + (size_t)(bm + srow) * K + scol;
  const u16* Bb = B + (size_t)(bn + srow) * K + scol;
  f32x4 acc[2][2];
#pragma unroll
  for (int i = 0; i < 2; ++i)
#pragma unroll
    for (int j = 0; j < 2; ++j) acc[i][j] = (f32x4){0.f, 0.f, 0.f, 0.f};
  const int fr = lane & 15, fq = lane >> 4, sw = fr & 7;

#pragma unroll
  for (int it = 0; it < 2; ++it) {
    gload_lds16(Ab + (size_t)(it * 32) * K, &As[0][wave * 512 + it * 2048]);
    gload_lds16(Bb + (size_t)(it * 32) * K, &Bs[0][wave * 512 + it * 2048]);
  }
  const int NIT = K >> 6;
  for (int itk = 0; itk < NIT; ++itk) {
    const int cur = itk & 1;
    __syncthreads();
    if (itk + 1 < NIT) {
      const int nk = (itk + 1) << 6;
      const int nxt = cur ^ 1;
#pragma unroll
      for (int it = 0; it < 2; ++it) {
        gload_lds16(Ab + (size_t)(it * 32) * K + nk, &As[nxt][wave * 512 + it * 2048]);
        gload_lds16(Bb + (size_t)(it * 32) * K + nk, &Bs[nxt][wave * 512 + it * 2048]);
      }
    }
#pragma unroll
    for (int kh = 0; kh < 2; ++kh) {
      bf16x8 af[2], bfv[2];
#pragma unroll
      for (int i = 0; i < 2; ++i)
        af[i] = *(const bf16x8*)(&As[cur][(wm + i * 16 + fr) * 64 + (((kh * 4 + fq) ^ sw) * 8)]);
#pragma unroll
      for (int j = 0; j < 2; ++j)
        bfv[j] = *(const bf16x8*)(&Bs[cur][(wn + j * 16 + fr) * 64 + (((kh * 4 + fq) ^ sw) * 8)]);
#pragma unroll
      for (int i = 0; i < 2; ++i)
#pragma unroll
        for (int j = 0; j < 2; ++j)
          acc[i][j] = __builtin_amdgcn_mfma_f32_16x16x32_bf16(af[i], bfv[j], acc[i][j], 0, 0, 0);
    }
  }
  const int orow = bm + wm + fq * 4;
  const int ocol = bn + wn + fr;
#pragma unroll
  for (int i = 0; i < 2; ++i)
#pragma unroll
    for (int j = 0; j < 2; ++j)
#pragma unroll
      for (int r = 0; r < 4; ++r)
        C[(size_t)(orow + i * 16 + r) * N + ocol + j * 16] = acc[i][j][r];
}

// ---------------- scalars + theta cumsum, per (b,h,kc): 512 blocks ---------
__device__ __forceinline__ float softplusf(float x) {
  return fmaxf(x, 0.f) + log1pf(expf(-fabsf(x)));
}

__global__ __launch_bounds__(1024) void theta_kernel(const float* __restrict__ tailF,
                                                     const float* __restrict__ dt_bias,
                                                     float4* __restrict__ sc4,
                                                     float4* __restrict__ theta4) {
  __shared__ float4 part[16];
  __shared__ float4 part2[16];
  const int blk = blockIdx.x;
  const int bh = blk >> 3, kc = blk & 7;
  const int b = bh >> 5, h = bh & 31;
  const int l = threadIdx.x;
  const int lane = l & 63, w = l >> 6;
  const float* trow = tailF + (size_t)(b * SEQ + l) * 128;
  float ddt = trow[h];
  float dt = softplusf(ddt + dt_bias[h]);
  if (kc == 0) {
    float dda = trow[32 + h];
    float trp = trow[64 + h];
    float a = fminf(-softplusf(dda), -1e-4f);
    float adt = a * dt;
    float lam = 1.0f / (1.0f + expf(-trp));
    sc4[(size_t)bh * SEQ + l] = make_float4(dt, expf(adt), lam, adt);
  }
  float4 v = *(const float4*)(trow + 96 + kc * 4);
  v.x *= dt; v.y *= dt; v.z *= dt; v.w *= dt;
#pragma unroll
  for (int off = 1; off < 64; off <<= 1) {
    float tx = __shfl_up(v.x, off, 64);
    float ty = __shfl_up(v.y, off, 64);
    float tz = __shfl_up(v.z, off, 64);
    float tw = __shfl_up(v.w, off, 64);
    if (lane >= off) { v.x += tx; v.y += ty; v.z += tz; v.w += tw; }
  }
  if (lane == 63) part[w] = v;
  __syncthreads();
  if (l < 16) {
    float4 p = part[l];
#pragma unroll
    for (int off = 1; off < 16; off <<= 1) {
      float tx = __shfl_up(p.x, off, 16);
      float ty = __shfl_up(p.y, off, 16);
      float tz = __shfl_up(p.z, off, 16);
      float tw = __shfl_up(p.w, off, 16);
      if (l >= off) { p.x += tx; p.y += ty; p.z += tz; p.w += tw; }
    }
    part2[l] = p;
  }
  __syncthreads();
  if (w > 0) {
    float4 o = part2[w - 1];
    v.x += o.x; v.y += o.y; v.z += o.z; v.w += o.w;
  }
  theta4[((size_t)(b * SEQ + l) * NHEADS + h) * 8 + kc] = v;
}

// ------- RMSNorm + bias + RoPE, fully parallel over (h,n): 1024 thr -------
__global__ __launch_bounds__(1024) void rope_kernel(const u16* __restrict__ proj16,
                                                    const float* __restrict__ theta,
                                                    const float* __restrict__ B_bias,
                                                    const float* __restrict__ C_bias,
                                                    const float* __restrict__ Bnw,
                                                    const float* __restrict__ Cnw,
                                                    u16* __restrict__ Bh,
                                                    u16* __restrict__ Ch) {
  const int bl = blockIdx.x;
  const int b = bl >> 10, l = bl & 1023;
  const int tid = threadIdx.x;
  __shared__ float sB[128], sC[128], red[4];
  __shared__ float cth[1024], sth[1024];
  float bv = 0.f, cv = 0.f;
  const size_t row = (size_t)bl * DPROJ;
  if (tid < 128) {
    bv = bf2f(proj16[row + OFF_B + tid]);
    cv = bf2f(proj16[row + OFF_C + tid]);
    float sb = bv * bv, sc = cv * cv;
    for (int m = 32; m; m >>= 1) { sb += __shfl_xor(sb, m); sc += __shfl_xor(sc, m); }
    const int wave = tid >> 6;
    if ((tid & 63) == 0) { red[wave * 2] = sb; red[wave * 2 + 1] = sc; }
  }
  {
    float th = theta[(size_t)bl * 1024 + tid];
    cth[tid] = cosf(th);
    sth[tid] = sinf(th);
  }
  __syncthreads();
  if (tid < 128) {
    float rb = rsqrtf((red[0] + red[2]) / 128.0f + 1e-5f);
    float rc = rsqrtf((red[1] + red[3]) / 128.0f + 1e-5f);
    sB[tid] = bv * rb * Bnw[tid];
    sC[tid] = cv * rc * Cnw[tid];
  }
  __syncthreads();
  const int h = tid >> 5;
  const int n0 = (tid & 31) * 4;
  float ob[4], oc[4];
  if (n0 < 32) {
#pragma unroll
    for (int j = 0; j < 4; ++j) {
      int n = n0 + j;
      float c = cth[h * 32 + n], s = sth[h * 32 + n];
      float b1 = sB[n] + B_bias[h * 128 + n];
      float b2 = sB[n + 32] + B_bias[h * 128 + n + 32];
      float c1 = sC[n] + C_bias[h * 128 + n];
      float c2 = sC[n + 32] + C_bias[h * 128 + n + 32];
      ob[j] = b1 * c - b2 * s;
      oc[j] = c1 * c - c2 * s;
    }
  } else if (n0 < 64) {
#pragma unroll
    for (int j = 0; j < 4; ++j) {
      int n = n0 + j, k = n - 32;
      float c = cth[h * 32 + k], s = sth[h * 32 + k];
      float b1 = sB[k] + B_bias[h * 128 + k];
      float b2 = sB[k + 32] + B_bias[h * 128 + k + 32];
      float c1 = sC[k] + C_bias[h * 128 + k];
      float c2 = sC[k + 32] + C_bias[h * 128 + k + 32];
      ob[j] = b1 * s + b2 * c;
      oc[j] = c1 * s + c2 * c;
    }
  } else {
#pragma unroll
    for (int j = 0; j < 4; ++j) {
      int n = n0 + j;
      ob[j] = sB[n] + B_bias[h * 128 + n];
      oc[j] = sC[n] + C_bias[h * 128 + n];
    }
  }
  size_t o = (((size_t)(b * NHEADS + h)) * SEQ + l) * DSTATE + n0;
  ushort4 vb = {f2bf(ob[0]), f2bf(ob[1]), f2bf(ob[2]), f2bf(ob[3])};
  ushort4 vc = {f2bf(oc[0]), f2bf(oc[1]), f2bf(oc[2]), f2bf(oc[3])};
  *(ushort4*)&Bh[o] = vb;
  *(ushort4*)&Ch[o] = vc;
}

// ============ chunked scan, phase A: MFMA per-chunk GEMMs ==============
#define SWB 136
#define SWS 72

__global__ __launch_bounds__(256) void chunk_kernel(
    const u16* __restrict__ proj16,
    const float4* __restrict__ sc4,
    const u16* __restrict__ Bh16,
    const u16* __restrict__ Ch16,
    u16* __restrict__ Ybuf,
    u16* __restrict__ dHT16,      // [bh][ch][64 p][128 n] bf16
    float* __restrict__ Gv_g,
    float2* __restrict__ de_g) {
  __shared__ u16 sCb[64 * SWB];
  __shared__ u16 sBb[64 * SWB];
  __shared__ u16 sBt[128 * SWS];
  __shared__ u16 sXt[64 * SWS];
  __shared__ u16 sSw[64 * SWS];
  __shared__ float sA[64], sW[64], sDL[64], sCV[64];

  const int blk = blockIdx.x;
  const int bh = blk >> 4, ch = blk & 15;
  const int b = bh >> 5, h = bh & 31;
  const int t0 = ch * CH;
  const int tid = threadIdx.x;
  const int lane = tid & 63, wave = tid >> 6;

  {
    const int row = tid >> 5;
    const int c4 = tid & 31;
#pragma unroll
    for (int pass = 0; pass < 8; ++pass) {
      int ll = pass * 8 + row;
      int l = t0 + ll;
      ushort4 cv = *(const ushort4*)&Ch16[((size_t)bh * SEQ + l) * DSTATE + c4 * 4];
      ushort4 bv = *(const ushort4*)&Bh16[((size_t)bh * SEQ + l) * DSTATE + c4 * 4];
      *(ushort4*)&sCb[ll * SWB + c4 * 4] = cv;
      *(ushort4*)&sBb[ll * SWB + c4 * 4] = bv;
      sBt[(c4 * 4 + 0) * SWS + ll] = bv.x;
      sBt[(c4 * 4 + 1) * SWS + ll] = bv.y;
      sBt[(c4 * 4 + 2) * SWS + ll] = bv.z;
      sBt[(c4 * 4 + 3) * SWS + ll] = bv.w;
    }
    const int xr = tid >> 2, xc = tid & 3;
    const u16* xrow = &proj16[(size_t)(b * SEQ + t0 + xr) * DPROJ + OFF_X + h * 64];
#pragma unroll
    for (int j = 0; j < 4; ++j) {
      ushort4 xv = *(const ushort4*)(xrow + xc * 16 + j * 4);
      int p = xc * 16 + j * 4;
      sXt[(p + 0) * SWS + xr] = xv.x;
      sXt[(p + 1) * SWS + xr] = xv.y;
      sXt[(p + 2) * SWS + xr] = xv.z;
      sXt[(p + 3) * SWS + xr] = xv.w;
    }
  }
  if (tid < 64) {
    float4 s = sc4[(size_t)bh * SEQ + t0 + tid];
    float dt = s.x, lam = s.z, adt = s.w;
    float A = adt;
#pragma unroll
    for (int off = 1; off < 64; off <<= 1) {
      float t = __shfl_up(A, off, 64);
      if (tid >= off) A += t;
    }
    float dtn = __shfl_down(dt, 1, 64);
    float lamn = __shfl_down(lam, 1, 64);
    float dl = dt * lam;
    float w = dl + dtn * (1.0f - lamn);
    if (tid == 63) w = 0.0f;
    float A63 = __shfl(A, 63, 64);
    float cv = (tid < 63) ? expf(A63 - A) * w : dl;
    sA[tid] = A; sW[tid] = w; sCV[tid] = cv; sDL[tid] = dl;
    Gv_g[((size_t)bh * NCH + ch) * 64 + tid] = expf(A);
    if (tid == 0) de_g[(size_t)bh * NCH + ch] = make_float2(expf(A63), dt * (1.0f - lam));
  }
  __syncthreads();

  const int fr = lane & 15, fq = lane >> 4;

  // S^T masked -> sSw[t][s] bf16
  {
    f32x4 acc[4];
#pragma unroll
    for (int j = 0; j < 4; ++j) acc[j] = (f32x4){0.f, 0.f, 0.f, 0.f};
#pragma unroll
    for (int kc = 0; kc < 4; ++kc) {
      bf16x8 af = *(const bf16x8*)&sBb[(wave * 16 + fr) * SWB + kc * 32 + fq * 8];
#pragma unroll
      for (int j = 0; j < 4; ++j) {
        bf16x8 bf = *(const bf16x8*)&sCb[(j * 16 + fr) * SWB + kc * 32 + fq * 8];
        acc[j] = __builtin_amdgcn_mfma_f32_16x16x32_bf16(af, bf, acc[j], 0, 0, 0);
      }
    }
    const int sbase = wave * 16 + fq * 4;
#pragma unroll
    for (int j = 0; j < 4; ++j) {
      int t = j * 16 + fr;
      float At = sA[t], dlt = sDL[t];
#pragma unroll
      for (int r = 0; r < 4; ++r) {
        int ss = sbase + r;
        float f = (ss < t) ? expf(At - sA[ss]) * sW[ss] : ((ss == t) ? dlt : 0.0f);
        sSw[t * SWS + ss] = f2bf(acc[j][r] * f);
      }
    }
  }
  __syncthreads();

  // Y1 = Sw @ X -> Ybuf (bf16)
  {
    f32x4 acc[4];
#pragma unroll
    for (int j = 0; j < 4; ++j) acc[j] = (f32x4){0.f, 0.f, 0.f, 0.f};
#pragma unroll
    for (int kc = 0; kc < 2; ++kc) {
      bf16x8 af = *(const bf16x8*)&sSw[(wave * 16 + fr) * SWS + kc * 32 + fq * 8];
#pragma unroll
      for (int j = 0; j < 4; ++j) {
        bf16x8 bf = *(const bf16x8*)&sXt[(j * 16 + fr) * SWS + kc * 32 + fq * 8];
        acc[j] = __builtin_amdgcn_mfma_f32_16x16x32_bf16(af, bf, acc[j], 0, 0, 0);
      }
    }
    const int tr = t0 + wave * 16 + fq * 4;
#pragma unroll
    for (int j = 0; j < 4; ++j) {
      int p = j * 16 + fr;
#pragma unroll
      for (int r = 0; r < 4; ++r)
        Ybuf[(size_t)(b * SEQ + tr + r) * DINNER + h * 64 + p] = f2bf(acc[j][r]);
    }
  }
  __syncthreads();

  // scale Xt columns by cv[s]
  {
    const int p = tid >> 2;
    const int s0 = (tid & 3) * 16;
#pragma unroll
    for (int k = 0; k < 16; ++k) {
      int s = s0 + k;
      sXt[p * SWS + s] = f2bf(bf2f(sXt[p * SWS + s]) * sCV[s]);
    }
  }
  __syncthreads();

  // dHT[p][n] = sum_s Xt[p][s] * Bt[n][s]
  {
    f32x4 acc[8];
#pragma unroll
    for (int j = 0; j < 8; ++j) acc[j] = (f32x4){0.f, 0.f, 0.f, 0.f};
#pragma unroll
    for (int kc = 0; kc < 2; ++kc) {
      bf16x8 af = *(const bf16x8*)&sXt[(wave * 16 + fr) * SWS + kc * 32 + fq * 8];
#pragma unroll
      for (int j = 0; j < 8; ++j) {
        bf16x8 bf = *(const bf16x8*)&sBt[(j * 16 + fr) * SWS + kc * 32 + fq * 8];
        acc[j] = __builtin_amdgcn_mfma_f32_16x16x32_bf16(af, bf, acc[j], 0, 0, 0);
      }
    }
    const int pr = wave * 16 + fq * 4;
#pragma unroll
    for (int j = 0; j < 8; ++j) {
      int n = j * 16 + fr;
#pragma unroll
      for (int r = 0; r < 4; ++r)
        dHT16[(((size_t)bh * NCH + ch) * 64 + pr + r) * 128 + n] = f2bf(acc[j][r]);
    }
  }
}

// ============ phase B: carry, 256 blocks (bh x 4 p-groups) ==========
__global__ __launch_bounds__(128) void carry_kernel(
    const u16* __restrict__ proj16,
    const u16* __restrict__ Bh16,
    const u16* __restrict__ dHT16,
    const float2* __restrict__ de_g,
    u16* __restrict__ Heff16) {
  const int blk = blockIdx.x;
  const int bh = blk >> 2, pg = blk & 3;
  const int b = bh >> 5, h = bh & 31;
  const int tid = threadIdx.x;
  const int p = pg * 16 + (tid >> 3);
  const int n0 = (tid & 7) * 16;
  float hreg[16] = {};
  for (int c = 0; c < NCH; ++c) {
    float2 de = de_g[bh * NCH + c];
    float heff[16];
    if (c == 0) {
#pragma unroll
      for (int j = 0; j < 16; ++j) heff[j] = 0.0f;
    } else {
      int lprev = c * CH - 1;
      float xp = bf2f(proj16[(size_t)(b * SEQ + lprev) * DPROJ + OFF_X + h * 64 + p]);
      float eBx = de.y * xp;
      const u16* Bp = &Bh16[((size_t)bh * SEQ + lprev) * DSTATE + n0];
#pragma unroll
      for (int j4 = 0; j4 < 4; ++j4) {
        ushort4 bv = *(const ushort4*)(Bp + j4 * 4);
        heff[j4 * 4 + 0] = hreg[j4 * 4 + 0] + eBx * bf2f(bv.x);
        heff[j4 * 4 + 1] = hreg[j4 * 4 + 1] + eBx * bf2f(bv.y);
        heff[j4 * 4 + 2] = hreg[j4 * 4 + 2] + eBx * bf2f(bv.z);
        heff[j4 * 4 + 3] = hreg[j4 * 4 + 3] + eBx * bf2f(bv.w);
      }
    }
    size_t base = (((size_t)bh * NCH + c) * 64 + p) * 128 + n0;
#pragma unroll
    for (int j4 = 0; j4 < 4; ++j4) {
      ushort4 o = {f2bf(heff[j4 * 4 + 0]), f2bf(heff[j4 * 4 + 1]),
                   f2bf(heff[j4 * 4 + 2]), f2bf(heff[j4 * 4 + 3])};
      *(ushort4*)&Heff16[base + j4 * 4] = o;
    }
#pragma unroll
    for (int j4 = 0; j4 < 4; ++j4) {
      ushort4 dh = *(const ushort4*)&dHT16[base + j4 * 4];
      hreg[j4 * 4 + 0] = de.x * heff[j4 * 4 + 0] + bf2f(dh.x);
      hreg[j4 * 4 + 1] = de.x * heff[j4 * 4 + 1] + bf2f(dh.y);
      hreg[j4 * 4 + 2] = de.x * heff[j4 * 4 + 2] + bf2f(dh.z);
      hreg[j4 * 4 + 3] = de.x * heff[j4 * 4 + 3] + bf2f(dh.w);
    }
  }
}

// ============ phase C: MFMA  Y = gate(Y1 + G*(Ch@Heff^T) + D*x) ============
__global__ __launch_bounds__(256) void inter_kernel(
    const u16* __restrict__ proj16,
    const u16* __restrict__ Ch16,
    const u16* __restrict__ Heff16,
    const float* __restrict__ Gv_g,
    const float* __restrict__ Dp,
    u16* __restrict__ Ybuf) {
  __shared__ u16 sCt[64 * SWB];
  __shared__ u16 sHe[64 * SWB];
  __shared__ float sGv[64];
  const int blk = blockIdx.x;
  const int bh = blk >> 4, ch = blk & 15;
  const int b = bh >> 5, h = bh & 31;
  const int t0 = ch * CH;
  const int tid = threadIdx.x;
  const int lane = tid & 63, wave = tid >> 6;
  {
    const int row = tid >> 2, seg = tid & 3;
    const u16* csrc = &Ch16[((size_t)bh * SEQ + t0 + row) * DSTATE + seg * 32];
    const u16* hsrc = &Heff16[(((size_t)bh * NCH + ch) * 64 + row) * 128 + seg * 32];
#pragma unroll
    for (int q = 0; q < 4; ++q) {
      *(ushort4*)&sCt[row * SWB + seg * 32 + q * 8]     = *(const ushort4*)(csrc + q * 8);
      *(ushort4*)&sCt[row * SWB + seg * 32 + q * 8 + 4] = *(const ushort4*)(csrc + q * 8 + 4);
      *(ushort4*)&sHe[row * SWB + seg * 32 + q * 8]     = *(const ushort4*)(hsrc + q * 8);
      *(ushort4*)&sHe[row * SWB + seg * 32 + q * 8 + 4] = *(const ushort4*)(hsrc + q * 8 + 4);
    }
    if (tid < 64) sGv[tid] = Gv_g[((size_t)bh * NCH + ch) * 64 + tid];
  }
  __syncthreads();
  const int fr = lane & 15, fq = lane >> 4;
  f32x4 acc[4];
#pragma unroll
  for (int j = 0; j < 4; ++j) acc[j] = (f32x4){0.f, 0.f, 0.f, 0.f};
#pragma unroll
  for (int kc = 0; kc < 4; ++kc) {
    bf16x8 af = *(const bf16x8*)&sCt[(wave * 16 + fr) * SWB + kc * 32 + fq * 8];
#pragma unroll
    for (int j = 0; j < 4; ++j) {
      bf16x8 bf = *(const bf16x8*)&sHe[(j * 16 + fr) * SWB + kc * 32 + fq * 8];
      acc[j] = __builtin_amdgcn_mfma_f32_16x16x32_bf16(af, bf, acc[j], 0, 0, 0);
    }
  }
  const float Dv = Dp[h];
#pragma unroll
  for (int r = 0; r < 4; ++r) {
    int tl = wave * 16 + fq * 4 + r;
    int l = t0 + tl;
    float gt = sGv[tl];
    size_t rowp = (size_t)(b * SEQ + l) * DPROJ;
    size_t yrow = (size_t)(b * SEQ + l) * DINNER + h * 64;
#pragma unroll
    for (int j = 0; j < 4; ++j) {
      int p = j * 16 + fr;
      float x = bf2f(proj16[rowp + OFF_X + h * 64 + p]);
      float z = bf2f(proj16[rowp + OFF_Z + h * 64 + p]);
      float y1 = bf2f(Ybuf[yrow + p]);
      float yy = y1 + gt * acc[j][r] + Dv * x;
      float sg = 1.0f / (1.0f + expf(-z));
      Ybuf[yrow + p] = f2bf(yy * z * sg);
    }
  }
}

extern "C" void kernel_launch(void* const* d_in, const int* in_sizes, int n_in,
                              void* d_out, int out_size, void* d_ws, size_t ws_size,
                              hipStream_t stream) {
  const float* u       = (const float*)d_in[0];
  const float* W_in    = (const float*)d_in[1];
  const float* W_out   = (const float*)d_in[2];
  const float* dt_bias = (const float*)d_in[3];
  const float* B_bias  = (const float*)d_in[4];
  const float* C_bias  = (const float*)d_in[5];
  const float* Bnw     = (const float*)d_in[6];
  const float* Cnw     = (const float*)d_in[7];
  const float* Dp      = (const float*)d_in[8];
  float* out = (float*)d_out;

  char* ws = (char*)d_ws;
  u16*    proj16 = (u16*)(ws);                      // 18,350,080
  float*  tailF  = (float*)(ws + 18350080);         //  1,048,576
  float4* sc4    = (float4*)(ws + 19398656);        //  1,048,576
  float*  theta  = (float*)(ws + 20447232);         //  8,388,608
  u16*    Bh16   = (u16*)(ws + 28835840);           // 16,777,216
  u16*    Ch16   = (u16*)(ws + 45613056);           // 16,777,216
  u16*    Ybuf   = (u16*)(ws + 62390272);           //  8,388,608
  u16*    dHT16  = (u16*)(ws + 70778880);           // 16,777,216
  u16*    Heff16 = (u16*)(ws + 87556096);           // 16,777,216
  float*  Gv     = (float*)(ws + 104333312);        //    262,144
  float2* deg    = (float2*)(ws + 104595456);       //      8,192
  u16*    ub16   = (u16*)(ws + 104603648);          //  4,194,304
  u16*    Wi16   = (u16*)(ws + 108797952);          //  9,175,040
  u16*    Wo16   = (u16*)(ws + 117972992);          //  4,194,304

  cvt_all<<<(N4_U + N4_WI + N4_WO + 255) / 256, 256, 0, stream>>>(
      u, W_in, W_out, ub16, Wi16, Wo16);
  gemm_proj64<<<dim3(DPROJ / 64, (BATCH * SEQ) / 64), 256, 0, stream>>>(
      ub16, Wi16, proj16, tailF, BATCH * SEQ, DPROJ, DMODEL);
  theta_kernel<<<BATCH * NHEADS * 8, 1024, 0, stream>>>(tailF, dt_bias, sc4, (float4*)theta);
  rope_kernel<<<BATCH * SEQ, 1024, 0, stream>>>(proj16, theta, B_bias, C_bias, Bnw, Cnw, Bh16, Ch16);
  chunk_kernel<<<BATCH * NHEADS * NCH, 256, 0, stream>>>(
      proj16, sc4, Bh16, Ch16, Ybuf, dHT16, Gv, deg);
  carry_kernel<<<BATCH * NHEADS * 4, 128, 0, stream>>>(proj16, Bh16, dHT16, deg, Heff16);
  inter_kernel<<<BATCH * NHEADS * NCH, 256, 0, stream>>>(
      proj16, Ch16, Heff16, Gv, Dp, Ybuf);
  gemm_out64<<<dim3(DMODEL / 64, (BATCH * SEQ) / 64), 256, 0, stream>>>(
      Ybuf, Wo16, out, BATCH * SEQ, DMODEL, DINNER);
}

// Round 13
// 230.926 us; speedup vs baseline: 1.0037x; 1.0037x over previous
//
#include <hip/hip_runtime.h>
#include <hip/hip_bf16.h>
#include <math.h>

#define BATCH 2
#define SEQ 1024
#define DMODEL 1024
#define DSTATE 128
#define HEADDIM 64
#define NHEADS 32
#define DINNER 2048
#define NUMANG 32
#define DPROJ 4480
#define CH 64
#define NCH 16
#define TAILSTART 4352
// proj row offsets (elements)
#define OFF_Z 0
#define OFF_X 2048
#define OFF_B 4096
#define OFF_C 4224
#define OFF_DT 4352
#define OFF_A 4384
#define OFF_TRAP 4416
#define OFF_ANG 4448

typedef __attribute__((ext_vector_type(8))) short bf16x8;
typedef __attribute__((ext_vector_type(4))) float f32x4;
typedef unsigned short u16;

__device__ __forceinline__ u16 f2bf(float f) {
  unsigned int u = __float_as_uint(f);
  u += 0x7FFFu + ((u >> 16) & 1u);
  return (u16)(u >> 16);
}
__device__ __forceinline__ float bf2f(u16 x) {
  return __uint_as_float(((unsigned int)x) << 16);
}

#define N4_U 524288
#define N4_WI 1146880
#define N4_WO 524288

__global__ __launch_bounds__(256) void cvt_all(const float* __restrict__ u,
                                               const float* __restrict__ Wi,
                                               const float* __restrict__ Wo,
                                               u16* __restrict__ ub16,
                                               u16* __restrict__ Wi16,
                                               u16* __restrict__ Wo16) {
  int i = blockIdx.x * 256 + threadIdx.x;
  const float4* src;
  ushort4* dst;
  int idx;
  if (i < N4_U) { src = (const float4*)u; dst = (ushort4*)ub16; idx = i; }
  else if (i < N4_U + N4_WI) { src = (const float4*)Wi; dst = (ushort4*)Wi16; idx = i - N4_U; }
  else if (i < N4_U + N4_WI + N4_WO) { src = (const float4*)Wo; dst = (ushort4*)Wo16; idx = i - N4_U - N4_WI; }
  else return;
  float4 v = src[idx];
  ushort4 o;
  o.x = f2bf(v.x); o.y = f2bf(v.y); o.z = f2bf(v.z); o.w = f2bf(v.w);
  dst[idx] = o;
}

__device__ __forceinline__ void gload_lds16(const void* g, void* l) {
  __builtin_amdgcn_global_load_lds(
      (const __attribute__((address_space(1))) unsigned int*)g,
      (__attribute__((address_space(3))) unsigned int*)l, 16, 0, 0);
}

// ==== 64x64-tile bf16 MFMA GEMM, C = A @ B^T, dbuf + 8x8 L2 swizzle ======
// grid: 1D, id -> 8x8 (m,n) square; GM=32, GN=70 (guard), 36 squares.
__global__ __launch_bounds__(256) void gemm_proj64(const u16* __restrict__ A,
                                                   const u16* __restrict__ B,
                                                   u16* __restrict__ Cb,
                                                   float* __restrict__ tailF,
                                                   int M, int N, int K) {
  __shared__ u16 As[2][64 * 64];
  __shared__ u16 Bs[2][64 * 64];
  const int id = blockIdx.x;
  const int sq = id >> 6;
  const int im = (id & 63) & 7, inn = (id & 63) >> 3;
  const int mblk = (sq & 3) * 8 + im;       // 0..31
  const int nblk = (sq >> 2) * 8 + inn;     // 0..71
  if (nblk >= 70) return;
  const int bm = mblk * 64, bn = nblk * 64;

  const int tid = threadIdx.x;
  const int lane = tid & 63, wave = tid >> 6;
  const int wm = (wave >> 1) * 32, wn = (wave & 1) * 32;
  const int srow = wave * 8 + (lane >> 3);
  const int scol = (((lane & 7) ^ ((lane >> 3) & 7)) * 8);
  const u16* Ab = A + (size_t)(bm + srow) * K + scol;
  const u16* Bb = B + (size_t)(bn + srow) * K + scol;
  f32x4 acc[2][2];
#pragma unroll
  for (int i = 0; i < 2; ++i)
#pragma unroll
    for (int j = 0; j < 2; ++j) acc[i][j] = (f32x4){0.f, 0.f, 0.f, 0.f};
  const int fr = lane & 15, fq = lane >> 4, sw = fr & 7;

#pragma unroll
  for (int it = 0; it < 2; ++it) {
    gload_lds16(Ab + (size_t)(it * 32) * K, &As[0][wave * 512 + it * 2048]);
    gload_lds16(Bb + (size_t)(it * 32) * K, &Bs[0][wave * 512 + it * 2048]);
  }
  const int NIT = K >> 6;
  for (int itk = 0; itk < NIT; ++itk) {
    const int cur = itk & 1;
    __syncthreads();
    if (itk + 1 < NIT) {
      const int nk = (itk + 1) << 6;
      const int nxt = cur ^ 1;
#pragma unroll
      for (int it = 0; it < 2; ++it) {
        gload_lds16(Ab + (size_t)(it * 32) * K + nk, &As[nxt][wave * 512 + it * 2048]);
        gload_lds16(Bb + (size_t)(it * 32) * K + nk, &Bs[nxt][wave * 512 + it * 2048]);
      }
    }
#pragma unroll
    for (int kh = 0; kh < 2; ++kh) {
      bf16x8 af[2], bfv[2];
#pragma unroll
      for (int i = 0; i < 2; ++i)
        af[i] = *(const bf16x8*)(&As[cur][(wm + i * 16 + fr) * 64 + (((kh * 4 + fq) ^ sw) * 8)]);
#pragma unroll
      for (int j = 0; j < 2; ++j)
        bfv[j] = *(const bf16x8*)(&Bs[cur][(wn + j * 16 + fr) * 64 + (((kh * 4 + fq) ^ sw) * 8)]);
#pragma unroll
      for (int i = 0; i < 2; ++i)
#pragma unroll
        for (int j = 0; j < 2; ++j)
          acc[i][j] = __builtin_amdgcn_mfma_f32_16x16x32_bf16(af[i], bfv[j], acc[i][j], 0, 0, 0);
    }
  }
  const int orow = bm + wm + fq * 4;
  const int ocol = bn + wn + fr;
  const bool tail = (bn >= TAILSTART);
#pragma unroll
  for (int i = 0; i < 2; ++i)
#pragma unroll
    for (int j = 0; j < 2; ++j)
#pragma unroll
      for (int r = 0; r < 4; ++r) {
        float v = acc[i][j][r];
        int row = orow + i * 16 + r, col = ocol + j * 16;
        Cb[(size_t)row * N + col] = f2bf(v);
        if (tail) tailF[(size_t)row * 128 + (col - TAILSTART)] = v;
      }
}

// grid: 1D 512 blocks, GM=32, GN=16 -> 8 squares exactly.
__global__ __launch_bounds__(256) void gemm_out64(const u16* __restrict__ A,
                                                  const u16* __restrict__ B,
                                                  float* __restrict__ C,
                                                  int M, int N, int K) {
  __shared__ u16 As[2][64 * 64];
  __shared__ u16 Bs[2][64 * 64];
  const int id = blockIdx.x;
  const int sq = id >> 6;
  const int im = (id & 63) & 7, inn = (id & 63) >> 3;
  const int mblk = (sq & 3) * 8 + im;       // 0..31
  const int nblk = (sq >> 2) * 8 + inn;     // 0..15
  const int bm = mblk * 64, bn = nblk * 64;

  const int tid = threadIdx.x;
  const int lane = tid & 63, wave = tid >> 6;
  const int wm = (wave >> 1) * 32, wn = (wave & 1) * 32;
  const int srow = wave * 8 + (lane >> 3);
  const int scol = (((lane & 7) ^ ((lane >> 3) & 7)) * 8);
  const u16* Ab = A + (size_t)(bm + srow) * K + scol;
  const u16* Bb = B + (size_t)(bn + srow) * K + scol;
  f32x4 acc[2][2];
#pragma unroll
  for (int i = 0; i < 2; ++i)
#pragma unroll
    for (int j = 0; j < 2; ++j) acc[i][j] = (f32x4){0.f, 0.f, 0.f, 0.f};
  const int fr = lane & 15, fq = lane >> 4, sw = fr & 7;

#pragma unroll
  for (int it = 0; it < 2; ++it) {
    gload_lds16(Ab + (size_t)(it * 32) * K, &As[0][wave * 512 + it * 2048]);
    gload_lds16(Bb + (size_t)(it * 32) * K, &Bs[0][wave * 512 + it * 2048]);
  }
  const int NIT = K >> 6;
  for (int itk = 0; itk < NIT; ++itk) {
    const int cur = itk & 1;
    __syncthreads();
    if (itk + 1 < NIT) {
      const int nk = (itk + 1) << 6;
      const int nxt = cur ^ 1;
#pragma unroll
      for (int it = 0; it < 2; ++it) {
        gload_lds16(Ab + (size_t)(it * 32) * K + nk, &As[nxt][wave * 512 + it * 2048]);
        gload_lds16(Bb + (size_t)(it * 32) * K + nk, &Bs[nxt][wave * 512 + it * 2048]);
      }
    }
#pragma unroll
    for (int kh = 0; kh < 2; ++kh) {
      bf16x8 af[2], bfv[2];
#pragma unroll
      for (int i = 0; i < 2; ++i)
        af[i] = *(const bf16x8*)(&As[cur][(wm + i * 16 + fr) * 64 + (((kh * 4 + fq) ^ sw) * 8)]);
#pragma unroll
      for (int j = 0; j < 2; ++j)
        bfv[j] = *(const bf16x8*)(&Bs[cur][(wn + j * 16 + fr) * 64 + (((kh * 4 + fq) ^ sw) * 8)]);
#pragma unroll
      for (int i = 0; i < 2; ++i)
#pragma unroll
        for (int j = 0; j < 2; ++j)
          acc[i][j] = __builtin_amdgcn_mfma_f32_16x16x32_bf16(af[i], bfv[j], acc[i][j], 0, 0, 0);
    }
  }
  const int orow = bm + wm + fq * 4;
  const int ocol = bn + wn + fr;
#pragma unroll
  for (int i = 0; i < 2; ++i)
#pragma unroll
    for (int j = 0; j < 2; ++j)
#pragma unroll
      for (int r = 0; r < 4; ++r)
        C[(size_t)(orow + i * 16 + r) * N + ocol + j * 16] = acc[i][j][r];
}

// ---------------- scalars + theta cumsum, per (b,h,kc): 512 blocks ---------
__device__ __forceinline__ float softplusf(float x) {
  return fmaxf(x, 0.f) + log1pf(expf(-fabsf(x)));
}

__global__ __launch_bounds__(1024) void theta_kernel(const float* __restrict__ tailF,
                                                     const float* __restrict__ dt_bias,
                                                     float4* __restrict__ sc4,
                                                     float4* __restrict__ theta4) {
  __shared__ float4 part[16];
  __shared__ float4 part2[16];
  const int blk = blockIdx.x;
  const int bh = blk >> 3, kc = blk & 7;
  const int b = bh >> 5, h = bh & 31;
  const int l = threadIdx.x;
  const int lane = l & 63, w = l >> 6;
  const float* trow = tailF + (size_t)(b * SEQ + l) * 128;
  float ddt = trow[h];
  float dt = softplusf(ddt + dt_bias[h]);
  if (kc == 0) {
    float dda = trow[32 + h];
    float trp = trow[64 + h];
    float a = fminf(-softplusf(dda), -1e-4f);
    float adt = a * dt;
    float lam = 1.0f / (1.0f + expf(-trp));
    sc4[(size_t)bh * SEQ + l] = make_float4(dt, expf(adt), lam, adt);
  }
  float4 v = *(const float4*)(trow + 96 + kc * 4);
  v.x *= dt; v.y *= dt; v.z *= dt; v.w *= dt;
#pragma unroll
  for (int off = 1; off < 64; off <<= 1) {
    float tx = __shfl_up(v.x, off, 64);
    float ty = __shfl_up(v.y, off, 64);
    float tz = __shfl_up(v.z, off, 64);
    float tw = __shfl_up(v.w, off, 64);
    if (lane >= off) { v.x += tx; v.y += ty; v.z += tz; v.w += tw; }
  }
  if (lane == 63) part[w] = v;
  __syncthreads();
  if (l < 16) {
    float4 p = part[l];
#pragma unroll
    for (int off = 1; off < 16; off <<= 1) {
      float tx = __shfl_up(p.x, off, 16);
      float ty = __shfl_up(p.y, off, 16);
      float tz = __shfl_up(p.z, off, 16);
      float tw = __shfl_up(p.w, off, 16);
      if (l >= off) { p.x += tx; p.y += ty; p.z += tz; p.w += tw; }
    }
    part2[l] = p;
  }
  __syncthreads();
  if (w > 0) {
    float4 o = part2[w - 1];
    v.x += o.x; v.y += o.y; v.z += o.z; v.w += o.w;
  }
  theta4[((size_t)(b * SEQ + l) * NHEADS + h) * 8 + kc] = v;
}

// ------- RMSNorm + bias + RoPE, fully parallel over (h,n): 1024 thr -------
__global__ __launch_bounds__(1024) void rope_kernel(const u16* __restrict__ proj16,
                                                    const float* __restrict__ theta,
                                                    const float* __restrict__ B_bias,
                                                    const float* __restrict__ C_bias,
                                                    const float* __restrict__ Bnw,
                                                    const float* __restrict__ Cnw,
                                                    u16* __restrict__ Bh,
                                                    u16* __restrict__ Ch) {
  const int bl = blockIdx.x;
  const int b = bl >> 10, l = bl & 1023;
  const int tid = threadIdx.x;
  __shared__ float sB[128], sC[128], red[4];
  __shared__ float cth[1024], sth[1024];
  float bv = 0.f, cv = 0.f;
  const size_t row = (size_t)bl * DPROJ;
  if (tid < 128) {
    bv = bf2f(proj16[row + OFF_B + tid]);
    cv = bf2f(proj16[row + OFF_C + tid]);
    float sb = bv * bv, sc = cv * cv;
    for (int m = 32; m; m >>= 1) { sb += __shfl_xor(sb, m); sc += __shfl_xor(sc, m); }
    const int wave = tid >> 6;
    if ((tid & 63) == 0) { red[wave * 2] = sb; red[wave * 2 + 1] = sc; }
  }
  {
    float th = theta[(size_t)bl * 1024 + tid];
    cth[tid] = cosf(th);
    sth[tid] = sinf(th);
  }
  __syncthreads();
  if (tid < 128) {
    float rb = rsqrtf((red[0] + red[2]) / 128.0f + 1e-5f);
    float rc = rsqrtf((red[1] + red[3]) / 128.0f + 1e-5f);
    sB[tid] = bv * rb * Bnw[tid];
    sC[tid] = cv * rc * Cnw[tid];
  }
  __syncthreads();
  const int h = tid >> 5;
  const int n0 = (tid & 31) * 4;
  float ob[4], oc[4];
  if (n0 < 32) {
#pragma unroll
    for (int j = 0; j < 4; ++j) {
      int n = n0 + j;
      float c = cth[h * 32 + n], s = sth[h * 32 + n];
      float b1 = sB[n] + B_bias[h * 128 + n];
      float b2 = sB[n + 32] + B_bias[h * 128 + n + 32];
      float c1 = sC[n] + C_bias[h * 128 + n];
      float c2 = sC[n + 32] + C_bias[h * 128 + n + 32];
      ob[j] = b1 * c - b2 * s;
      oc[j] = c1 * c - c2 * s;
    }
  } else if (n0 < 64) {
#pragma unroll
    for (int j = 0; j < 4; ++j) {
      int n = n0 + j, k = n - 32;
      float c = cth[h * 32 + k], s = sth[h * 32 + k];
      float b1 = sB[k] + B_bias[h * 128 + k];
      float b2 = sB[k + 32] + B_bias[h * 128 + k + 32];
      float c1 = sC[k] + C_bias[h * 128 + k];
      float c2 = sC[k + 32] + C_bias[h * 128 + k + 32];
      ob[j] = b1 * s + b2 * c;
      oc[j] = c1 * s + c2 * c;
    }
  } else {
#pragma unroll
    for (int j = 0; j < 4; ++j) {
      int n = n0 + j;
      ob[j] = sB[n] + B_bias[h * 128 + n];
      oc[j] = sC[n] + C_bias[h * 128 + n];
    }
  }
  size_t o = (((size_t)(b * NHEADS + h)) * SEQ + l) * DSTATE + n0;
  ushort4 vb = {f2bf(ob[0]), f2bf(ob[1]), f2bf(ob[2]), f2bf(ob[3])};
  ushort4 vc = {f2bf(oc[0]), f2bf(oc[1]), f2bf(oc[2]), f2bf(oc[3])};
  *(ushort4*)&Bh[o] = vb;
  *(ushort4*)&Ch[o] = vc;
}

// ============ chunked scan, phase A: MFMA per-chunk GEMMs ==============
#define SWB 136
#define SWS 72

__global__ __launch_bounds__(256) void chunk_kernel(
    const u16* __restrict__ proj16,
    const float4* __restrict__ sc4,
    const u16* __restrict__ Bh16,
    const u16* __restrict__ Ch16,
    u16* __restrict__ Ybuf,
    u16* __restrict__ dHT16,      // [bh][ch][64 p][128 n] bf16
    float* __restrict__ Gv_g,
    float2* __restrict__ de_g) {
  __shared__ u16 sCb[64 * SWB];
  __shared__ u16 sBb[64 * SWB];
  __shared__ u16 sBt[128 * SWS];
  __shared__ u16 sXt[64 * SWS];
  __shared__ u16 sSw[64 * SWS];
  __shared__ float sA[64], sW[64], sDL[64], sCV[64];

  const int blk = blockIdx.x;
  const int bh = blk >> 4, ch = blk & 15;
  const int b = bh >> 5, h = bh & 31;
  const int t0 = ch * CH;
  const int tid = threadIdx.x;
  const int lane = tid & 63, wave = tid >> 6;

  {
    const int row = tid >> 5;
    const int c4 = tid & 31;
#pragma unroll
    for (int pass = 0; pass < 8; ++pass) {
      int ll = pass * 8 + row;
      int l = t0 + ll;
      ushort4 cv = *(const ushort4*)&Ch16[((size_t)bh * SEQ + l) * DSTATE + c4 * 4];
      ushort4 bv = *(const ushort4*)&Bh16[((size_t)bh * SEQ + l) * DSTATE + c4 * 4];
      *(ushort4*)&sCb[ll * SWB + c4 * 4] = cv;
      *(ushort4*)&sBb[ll * SWB + c4 * 4] = bv;
      sBt[(c4 * 4 + 0) * SWS + ll] = bv.x;
      sBt[(c4 * 4 + 1) * SWS + ll] = bv.y;
      sBt[(c4 * 4 + 2) * SWS + ll] = bv.z;
      sBt[(c4 * 4 + 3) * SWS + ll] = bv.w;
    }
    const int xr = tid >> 2, xc = tid & 3;
    const u16* xrow = &proj16[(size_t)(b * SEQ + t0 + xr) * DPROJ + OFF_X + h * 64];
#pragma unroll
    for (int j = 0; j < 4; ++j) {
      ushort4 xv = *(const ushort4*)(xrow + xc * 16 + j * 4);
      int p = xc * 16 + j * 4;
      sXt[(p + 0) * SWS + xr] = xv.x;
      sXt[(p + 1) * SWS + xr] = xv.y;
      sXt[(p + 2) * SWS + xr] = xv.z;
      sXt[(p + 3) * SWS + xr] = xv.w;
    }
  }
  if (tid < 64) {
    float4 s = sc4[(size_t)bh * SEQ + t0 + tid];
    float dt = s.x, lam = s.z, adt = s.w;
    float A = adt;
#pragma unroll
    for (int off = 1; off < 64; off <<= 1) {
      float t = __shfl_up(A, off, 64);
      if (tid >= off) A += t;
    }
    float dtn = __shfl_down(dt, 1, 64);
    float lamn = __shfl_down(lam, 1, 64);
    float dl = dt * lam;
    float w = dl + dtn * (1.0f - lamn);
    if (tid == 63) w = 0.0f;
    float A63 = __shfl(A, 63, 64);
    float cv = (tid < 63) ? expf(A63 - A) * w : dl;
    sA[tid] = A; sW[tid] = w; sCV[tid] = cv; sDL[tid] = dl;
    Gv_g[((size_t)bh * NCH + ch) * 64 + tid] = expf(A);
    if (tid == 0) de_g[(size_t)bh * NCH + ch] = make_float2(expf(A63), dt * (1.0f - lam));
  }
  __syncthreads();

  const int fr = lane & 15, fq = lane >> 4;

  // S^T masked -> sSw[t][s] bf16
  {
    f32x4 acc[4];
#pragma unroll
    for (int j = 0; j < 4; ++j) acc[j] = (f32x4){0.f, 0.f, 0.f, 0.f};
#pragma unroll
    for (int kc = 0; kc < 4; ++kc) {
      bf16x8 af = *(const bf16x8*)&sBb[(wave * 16 + fr) * SWB + kc * 32 + fq * 8];
#pragma unroll
      for (int j = 0; j < 4; ++j) {
        bf16x8 bf = *(const bf16x8*)&sCb[(j * 16 + fr) * SWB + kc * 32 + fq * 8];
        acc[j] = __builtin_amdgcn_mfma_f32_16x16x32_bf16(af, bf, acc[j], 0, 0, 0);
      }
    }
    const int sbase = wave * 16 + fq * 4;
#pragma unroll
    for (int j = 0; j < 4; ++j) {
      int t = j * 16 + fr;
      float At = sA[t], dlt = sDL[t];
#pragma unroll
      for (int r = 0; r < 4; ++r) {
        int ss = sbase + r;
        float f = (ss < t) ? expf(At - sA[ss]) * sW[ss] : ((ss == t) ? dlt : 0.0f);
        sSw[t * SWS + ss] = f2bf(acc[j][r] * f);
      }
    }
  }
  __syncthreads();

  // Y1 = Sw @ X -> Ybuf (bf16)
  {
    f32x4 acc[4];
#pragma unroll
    for (int j = 0; j < 4; ++j) acc[j] = (f32x4){0.f, 0.f, 0.f, 0.f};
#pragma unroll
    for (int kc = 0; kc < 2; ++kc) {
      bf16x8 af = *(const bf16x8*)&sSw[(wave * 16 + fr) * SWS + kc * 32 + fq * 8];
#pragma unroll
      for (int j = 0; j < 4; ++j) {
        bf16x8 bf = *(const bf16x8*)&sXt[(j * 16 + fr) * SWS + kc * 32 + fq * 8];
        acc[j] = __builtin_amdgcn_mfma_f32_16x16x32_bf16(af, bf, acc[j], 0, 0, 0);
      }
    }
    const int tr = t0 + wave * 16 + fq * 4;
#pragma unroll
    for (int j = 0; j < 4; ++j) {
      int p = j * 16 + fr;
#pragma unroll
      for (int r = 0; r < 4; ++r)
        Ybuf[(size_t)(b * SEQ + tr + r) * DINNER + h * 64 + p] = f2bf(acc[j][r]);
    }
  }
  __syncthreads();

  // scale Xt columns by cv[s]
  {
    const int p = tid >> 2;
    const int s0 = (tid & 3) * 16;
#pragma unroll
    for (int k = 0; k < 16; ++k) {
      int s = s0 + k;
      sXt[p * SWS + s] = f2bf(bf2f(sXt[p * SWS + s]) * sCV[s]);
    }
  }
  __syncthreads();

  // dHT[p][n] = sum_s Xt[p][s] * Bt[n][s]
  {
    f32x4 acc[8];
#pragma unroll
    for (int j = 0; j < 8; ++j) acc[j] = (f32x4){0.f, 0.f, 0.f, 0.f};
#pragma unroll
    for (int kc = 0; kc < 2; ++kc) {
      bf16x8 af = *(const bf16x8*)&sXt[(wave * 16 + fr) * SWS + kc * 32 + fq * 8];
#pragma unroll
      for (int j = 0; j < 8; ++j) {
        bf16x8 bf = *(const bf16x8*)&sBt[(j * 16 + fr) * SWS + kc * 32 + fq * 8];
        acc[j] = __builtin_amdgcn_mfma_f32_16x16x32_bf16(af, bf, acc[j], 0, 0, 0);
      }
    }
    const int pr = wave * 16 + fq * 4;
#pragma unroll
    for (int j = 0; j < 8; ++j) {
      int n = j * 16 + fr;
#pragma unroll
      for (int r = 0; r < 4; ++r)
        dHT16[(((size_t)bh * NCH + ch) * 64 + pr + r) * 128 + n] = f2bf(acc[j][r]);
    }
  }
}

// ============ phase B: carry, 256 blocks (bh x 4 p-groups) ==========
__global__ __launch_bounds__(128) void carry_kernel(
    const u16* __restrict__ proj16,
    const u16* __restrict__ Bh16,
    const u16* __restrict__ dHT16,
    const float2* __restrict__ de_g,
    u16* __restrict__ Heff16) {
  const int blk = blockIdx.x;
  const int bh = blk >> 2, pg = blk & 3;
  const int b = bh >> 5, h = bh & 31;
  const int tid = threadIdx.x;
  const int p = pg * 16 + (tid >> 3);
  const int n0 = (tid & 7) * 16;
  float hreg[16] = {};
  for (int c = 0; c < NCH; ++c) {
    float2 de = de_g[bh * NCH + c];
    float heff[16];
    if (c == 0) {
#pragma unroll
      for (int j = 0; j < 16; ++j) heff[j] = 0.0f;
    } else {
      int lprev = c * CH - 1;
      float xp = bf2f(proj16[(size_t)(b * SEQ + lprev) * DPROJ + OFF_X + h * 64 + p]);
      float eBx = de.y * xp;
      const u16* Bp = &Bh16[((size_t)bh * SEQ + lprev) * DSTATE + n0];
#pragma unroll
      for (int j4 = 0; j4 < 4; ++j4) {
        ushort4 bv = *(const ushort4*)(Bp + j4 * 4);
        heff[j4 * 4 + 0] = hreg[j4 * 4 + 0] + eBx * bf2f(bv.x);
        heff[j4 * 4 + 1] = hreg[j4 * 4 + 1] + eBx * bf2f(bv.y);
        heff[j4 * 4 + 2] = hreg[j4 * 4 + 2] + eBx * bf2f(bv.z);
        heff[j4 * 4 + 3] = hreg[j4 * 4 + 3] + eBx * bf2f(bv.w);
      }
    }
    size_t base = (((size_t)bh * NCH + c) * 64 + p) * 128 + n0;
#pragma unroll
    for (int j4 = 0; j4 < 4; ++j4) {
      ushort4 o = {f2bf(heff[j4 * 4 + 0]), f2bf(heff[j4 * 4 + 1]),
                   f2bf(heff[j4 * 4 + 2]), f2bf(heff[j4 * 4 + 3])};
      *(ushort4*)&Heff16[base + j4 * 4] = o;
    }
#pragma unroll
    for (int j4 = 0; j4 < 4; ++j4) {
      ushort4 dh = *(const ushort4*)&dHT16[base + j4 * 4];
      hreg[j4 * 4 + 0] = de.x * heff[j4 * 4 + 0] + bf2f(dh.x);
      hreg[j4 * 4 + 1] = de.x * heff[j4 * 4 + 1] + bf2f(dh.y);
      hreg[j4 * 4 + 2] = de.x * heff[j4 * 4 + 2] + bf2f(dh.z);
      hreg[j4 * 4 + 3] = de.x * heff[j4 * 4 + 3] + bf2f(dh.w);
    }
  }
}

// ============ phase C: MFMA  Y = gate(Y1 + G*(Ch@Heff^T) + D*x) ============
__global__ __launch_bounds__(256) void inter_kernel(
    const u16* __restrict__ proj16,
    const u16* __restrict__ Ch16,
    const u16* __restrict__ Heff16,
    const float* __restrict__ Gv_g,
    const float* __restrict__ Dp,
    u16* __restrict__ Ybuf) {
  __shared__ u16 sCt[64 * SWB];
  __shared__ u16 sHe[64 * SWB];
  __shared__ float sGv[64];
  const int blk = blockIdx.x;
  const int bh = blk >> 4, ch = blk & 15;
  const int b = bh >> 5, h = bh & 31;
  const int t0 = ch * CH;
  const int tid = threadIdx.x;
  const int lane = tid & 63, wave = tid >> 6;
  {
    const int row = tid >> 2, seg = tid & 3;
    const u16* csrc = &Ch16[((size_t)bh * SEQ + t0 + row) * DSTATE + seg * 32];
    const u16* hsrc = &Heff16[(((size_t)bh * NCH + ch) * 64 + row) * 128 + seg * 32];
#pragma unroll
    for (int q = 0; q < 4; ++q) {
      *(ushort4*)&sCt[row * SWB + seg * 32 + q * 8]     = *(const ushort4*)(csrc + q * 8);
      *(ushort4*)&sCt[row * SWB + seg * 32 + q * 8 + 4] = *(const ushort4*)(csrc + q * 8 + 4);
      *(ushort4*)&sHe[row * SWB + seg * 32 + q * 8]     = *(const ushort4*)(hsrc + q * 8);
      *(ushort4*)&sHe[row * SWB + seg * 32 + q * 8 + 4] = *(const ushort4*)(hsrc + q * 8 + 4);
    }
    if (tid < 64) sGv[tid] = Gv_g[((size_t)bh * NCH + ch) * 64 + tid];
  }
  __syncthreads();
  const int fr = lane & 15, fq = lane >> 4;
  f32x4 acc[4];
#pragma unroll
  for (int j = 0; j < 4; ++j) acc[j] = (f32x4){0.f, 0.f, 0.f, 0.f};
#pragma unroll
  for (int kc = 0; kc < 4; ++kc) {
    bf16x8 af = *(const bf16x8*)&sCt[(wave * 16 + fr) * SWB + kc * 32 + fq * 8];
#pragma unroll
    for (int j = 0; j < 4; ++j) {
      bf16x8 bf = *(const bf16x8*)&sHe[(j * 16 + fr) * SWB + kc * 32 + fq * 8];
      acc[j] = __builtin_amdgcn_mfma_f32_16x16x32_bf16(af, bf, acc[j], 0, 0, 0);
    }
  }
  const float Dv = Dp[h];
#pragma unroll
  for (int r = 0; r < 4; ++r) {
    int tl = wave * 16 + fq * 4 + r;
    int l = t0 + tl;
    float gt = sGv[tl];
    size_t rowp = (size_t)(b * SEQ + l) * DPROJ;
    size_t yrow = (size_t)(b * SEQ + l) * DINNER + h * 64;
#pragma unroll
    for (int j = 0; j < 4; ++j) {
      int p = j * 16 + fr;
      float x = bf2f(proj16[rowp + OFF_X + h * 64 + p]);
      float z = bf2f(proj16[rowp + OFF_Z + h * 64 + p]);
      float y1 = bf2f(Ybuf[yrow + p]);
      float yy = y1 + gt * acc[j][r] + Dv * x;
      float sg = 1.0f / (1.0f + expf(-z));
      Ybuf[yrow + p] = f2bf(yy * z * sg);
    }
  }
}

extern "C" void kernel_launch(void* const* d_in, const int* in_sizes, int n_in,
                              void* d_out, int out_size, void* d_ws, size_t ws_size,
                              hipStream_t stream) {
  const float* u       = (const float*)d_in[0];
  const float* W_in    = (const float*)d_in[1];
  const float* W_out   = (const float*)d_in[2];
  const float* dt_bias = (const float*)d_in[3];
  const float* B_bias  = (const float*)d_in[4];
  const float* C_bias  = (const float*)d_in[5];
  const float* Bnw     = (const float*)d_in[6];
  const float* Cnw     = (const float*)d_in[7];
  const float* Dp      = (const float*)d_in[8];
  float* out = (float*)d_out;

  char* ws = (char*)d_ws;
  u16*    proj16 = (u16*)(ws);                      // 18,350,080
  float*  tailF  = (float*)(ws + 18350080);         //  1,048,576
  float4* sc4    = (float4*)(ws + 19398656);        //  1,048,576
  float*  theta  = (float*)(ws + 20447232);         //  8,388,608
  u16*    Bh16   = (u16*)(ws + 28835840);           // 16,777,216
  u16*    Ch16   = (u16*)(ws + 45613056);           // 16,777,216
  u16*    Ybuf   = (u16*)(ws + 62390272);           //  8,388,608
  u16*    dHT16  = (u16*)(ws + 70778880);           // 16,777,216
  u16*    Heff16 = (u16*)(ws + 87556096);           // 16,777,216
  float*  Gv     = (float*)(ws + 104333312);        //    262,144
  float2* deg    = (float2*)(ws + 104595456);       //      8,192
  u16*    ub16   = (u16*)(ws + 104603648);          //  4,194,304
  u16*    Wi16   = (u16*)(ws + 108797952);          //  9,175,040
  u16*    Wo16   = (u16*)(ws + 117972992);          //  4,194,304

  cvt_all<<<(N4_U + N4_WI + N4_WO + 255) / 256, 256, 0, stream>>>(
      u, W_in, W_out, ub16, Wi16, Wo16);
  gemm_proj64<<<36 * 64, 256, 0, stream>>>(
      ub16, Wi16, proj16, tailF, BATCH * SEQ, DPROJ, DMODEL);
  theta_kernel<<<BATCH * NHEADS * 8, 1024, 0, stream>>>(tailF, dt_bias, sc4, (float4*)theta);
  rope_kernel<<<BATCH * SEQ, 1024, 0, stream>>>(proj16, theta, B_bias, C_bias, Bnw, Cnw, Bh16, Ch16);
  chunk_kernel<<<BATCH * NHEADS * NCH, 256, 0, stream>>>(
      proj16, sc4, Bh16, Ch16, Ybuf, dHT16, Gv, deg);
  carry_kernel<<<BATCH * NHEADS * 4, 128, 0, stream>>>(proj16, Bh16, dHT16, deg, Heff16);
  inter_kernel<<<BATCH * NHEADS * NCH, 256, 0, stream>>>(
      proj16, Ch16, Heff16, Gv, Dp, Ybuf);
  gemm_out64<<<8 * 64, 256, 0, stream>>>(
      Ybuf, Wo16, out, BATCH * SEQ, DMODEL, DINNER);
}